// Round 16
// baseline (17.093 us; speedup 1.0000x reference)
//
#include <hip/hip_runtime.h>
#include <math.h>

#define NATOMS 32
#define NMOL   64
#define MAXPC  465     // C(31,2)
#define RCRf 5.2f
#define RCAf 3.5f

// ONE-ROUND layout: 2048 blocks x 256 threads (4 waves) = 8 blocks/CU x 256 CU,
// all co-resident (launch_bounds(256,8) caps VGPR at 64; LDS 16.1KB/block).
// A (wave 0): atom setup; ballot compaction BY COMPACT INDEX (R13-proven).
// B1 (p=tid stride 256, typ 1 pass): decode-only -> px histogram.
//    radial on tid 128..191 in the same window (overlaps B1; usually idle there).
// B2: re-decode + build record {f1[0..7] bf16-packed, f2f[0..3] f32} ->
//    bucket-sorted slot (register prefix + atomicAdd rank), 2x b128 write.
// E: angular feature g=tid (0..255) and g=tid+64 for tid>=192 (256..319);
//    scan only bucket g>>5: 2 LDS reads + bf16 unpack + fma per record.
__global__ __launch_bounds__(256, 8) void aev_kernel(const int* __restrict__ species,
                                                     const float* __restrict__ coords,
                                                     float* __restrict__ out) {
    const int bid = blockIdx.x;
    const int n = bid >> 5;
    const int i = bid & 31;
    const int tid = threadIdx.x;

    __shared__ float4   s_catom[NATOMS];         // compacted: dx,dy,dz,d
    __shared__ float2   s_cfs[NATOMS];           // compacted: fca, species
    __shared__ float2   s_dfr[NATOMS];           // orig idx: d, fcr (radial)
    __shared__ int      s_sp[NATOMS];
    __shared__ unsigned s_rec[MAXPC*8];          // 4 dw bf16-f1 + 4 dw f32-f2f
    __shared__ int      s_cnt[10], s_rank[10], s_nn;

    if (tid >= 64 && tid < 74)  s_cnt[tid-64]  = 0;
    if (tid >= 74 && tid < 84)  s_rank[tid-74] = 0;

    // ---------- phase A (wave 0) ----------
    if (tid < 64) {
        float fca_v = 0.f, sv = 0.f;
        float4 av = make_float4(0.f, 0.f, 0.f, 0.f);
        if (tid < NATOMS) {
            const float* cb = coords + (size_t)n*NATOMS*3;
            float dx = cb[tid*3+0] - cb[i*3+0];
            float dy = cb[tid*3+1] - cb[i*3+1];
            float dz = cb[tid*3+2] - cb[i*3+2];
            float d2 = dx*dx + dy*dy + dz*dz;
            float d  = sqrtf(d2 > 0.f ? d2 : 1.f);   // ref's where(d2>0,d2,1) guard
            bool self = (tid == i);
            float fr = (!self && d <= RCRf) ? (0.5f*__cosf(((float)M_PI/RCRf)*d) + 0.5f) : 0.f;
            fca_v    = (!self && d <= RCAf) ? (0.5f*__cosf(((float)M_PI/RCAf)*d) + 0.5f) : 0.f;
            int spv = species[n*NATOMS + tid];
            s_dfr[tid] = make_float2(d, fr);
            s_sp[tid]  = spv;
            av = make_float4(dx, dy, dz, d);
            sv = (float)spv;
        }
        unsigned long long m = __ballot(fca_v > 0.f);  // full-wave-active context
        int ci = (int)__popcll(m & ((1ull << tid) - 1ull));
        if (fca_v > 0.f) { s_catom[ci] = av; s_cfs[ci] = make_float2(fca_v, sv); }
        if (tid == 0) s_nn = (int)__popcll(m);
    }
    __syncthreads();                                   // barrier 1

    const int nn  = s_nn;
    const int cnt = (nn*(nn-1)) >> 1;                  // <= 465
    const int M   = 2*nn - 1;
    float* oa = out + NMOL*NATOMS + (size_t)bid * 384;

    if (tid == 255) out[bid] = (float)s_sp[i];         // output 0: species

    // ---------- B1: decode-only histogram ----------
    for (int p = tid; p < cnt; p += 256) {
        float t = sqrtf((float)(M*M - 8*p));
        int jj = (int)(((float)M - t) * 0.5f);
        jj = max(0, min(jj, nn-2));
        while (jj*(2*nn-jj-1)/2 > p) --jj;             // <=2 fixup steps
        while ((jj+1)*(2*nn-jj-2)/2 <= p) ++jj;
        int kk = p - jj*(2*nn-jj-1)/2 + jj + 1;
        int sj = (int)s_cfs[jj].y, sk = (int)s_cfs[kk].y;
        int lo = min(sj, sk), hi = max(sj, sk);
        int px = ((lo*(9-lo)) >> 1) + (hi - lo);       // triu pair index, S=4
        atomicAdd(&s_cnt[px], 1);
    }

    // ---------- radial (tid 128..191): overlaps B1 window ----------
    if (tid >= 128 && tid < 192) {
        const int f  = tid - 128;
        const int rs = f >> 4;
        const float shr = 0.9f + 0.26875f * (float)(f & 15);   // SHF_R
        float racc = 0.f;
        #pragma unroll 8
        for (int j = 0; j < NATOMS; ++j) {
            float2 dfr = s_dfr[j];                     // fr==0 encodes mask
            float dm = dfr.x - shr;
            racc += (s_sp[j] == rs) ? 0.25f * __expf(-16.f*dm*dm) * dfr.y : 0.f;
        }
        oa[f] = racc;
    }
    __syncthreads();                                   // barrier 2

    // counts broadcast; prefix via explicit selects (no runtime-indexed arrays)
    const int c0 = s_cnt[0], c1 = s_cnt[1], c2 = s_cnt[2], c3 = s_cnt[3], c4 = s_cnt[4];
    const int c5 = s_cnt[5], c6 = s_cnt[6], c7 = s_cnt[7], c8 = s_cnt[8], c9 = s_cnt[9];
    #define PREFIX(B) ( ((B) > 0 ? c0 : 0) + ((B) > 1 ? c1 : 0) + ((B) > 2 ? c2 : 0) \
                      + ((B) > 3 ? c3 : 0) + ((B) > 4 ? c4 : 0) + ((B) > 5 ? c5 : 0) \
                      + ((B) > 6 ? c6 : 0) + ((B) > 7 ? c7 : 0) + ((B) > 8 ? c8 : 0) )
    #define COUNT(B)  ( (B)==0?c0 : (B)==1?c1 : (B)==2?c2 : (B)==3?c3 : (B)==4?c4 \
                      : (B)==5?c5 : (B)==6?c6 : (B)==7?c7 : (B)==8?c8 : c9 )

    // ---------- B2: build + bucket-sorted place ----------
    const float CZ[8] = { 0.98078528f,  0.83146961f,  0.55557023f,  0.19509032f,
                         -0.19509032f, -0.55557023f, -0.83146961f, -0.98078528f};
    const float SZ[8] = { 0.19509032f,  0.55557023f,  0.83146961f,  0.98078528f,
                          0.98078528f,  0.83146961f,  0.55557023f,  0.19509032f};
    const float SHA[4] = {0.9f, 1.55f, 2.2f, 2.85f};

    for (int p = tid; p < cnt; p += 256) {
        float t = sqrtf((float)(M*M - 8*p));
        int jj = (int)(((float)M - t) * 0.5f);
        jj = max(0, min(jj, nn-2));
        while (jj*(2*nn-jj-1)/2 > p) --jj;
        while ((jj+1)*(2*nn-jj-2)/2 <= p) ++jj;
        int kk = p - jj*(2*nn-jj-1)/2 + jj + 1;
        float4 aj = s_catom[jj], ak = s_catom[kk];
        float2 fj = s_cfs[jj],  fk = s_cfs[kk];
        float fc2 = 2.f * fj.x * fk.x;
        float dot = aj.x*ak.x + aj.y*ak.y + aj.z*ak.z;
        float cv = 0.95f * dot * __builtin_amdgcn_rcpf(aj.w * ak.w);
        cv = fminf(0.95f, fmaxf(-0.95f, cv));
        float sv = sqrtf(1.f - cv*cv);                 // sin(acos(c))
        float dmean = 0.5f * (aj.w + ak.w);
        int sj = (int)fj.y, sk = (int)fk.y;
        int lo = min(sj, sk), hi = max(sj, sk);
        int px = ((lo*(9-lo)) >> 1) + (hi - lo);
        float f1[8];
        #pragma unroll
        for (int z = 0; z < 8; ++z) {
            float x = 0.5f + 0.5f*(cv*CZ[z] + sv*SZ[z]);   // (1+cos(th-sz))/2
            float q = x*x; q *= q; q *= q; q *= q; q *= q; // ^32
            f1[z] = q;
        }
        uint4 u;                                           // bf16 RTN pairs
        u.x = ((__float_as_uint(f1[0]) + 0x8000u) >> 16) | (((__float_as_uint(f1[1]) + 0x8000u) >> 16) << 16);
        u.y = ((__float_as_uint(f1[2]) + 0x8000u) >> 16) | (((__float_as_uint(f1[3]) + 0x8000u) >> 16) << 16);
        u.z = ((__float_as_uint(f1[4]) + 0x8000u) >> 16) | (((__float_as_uint(f1[5]) + 0x8000u) >> 16) << 16);
        u.w = ((__float_as_uint(f1[6]) + 0x8000u) >> 16) | (((__float_as_uint(f1[7]) + 0x8000u) >> 16) << 16);
        float4 v2;
        float dm0 = dmean - SHA[0], dm1 = dmean - SHA[1];
        float dm2 = dmean - SHA[2], dm3 = dmean - SHA[3];
        v2.x = __expf(-8.f*dm0*dm0) * fc2;
        v2.y = __expf(-8.f*dm1*dm1) * fc2;
        v2.z = __expf(-8.f*dm2*dm2) * fc2;
        v2.w = __expf(-8.f*dm3*dm3) * fc2;
        int slot = PREFIX(px) + atomicAdd(&s_rank[px], 1);
        unsigned* r = &s_rec[slot*8];
        *(uint4*)r        = u;
        *(float4*)(r + 4) = v2;
    }
    __syncthreads();                                   // barrier 3

    // ---------- E: angular feature ownership ----------
    {
        const int g = tid;                             // feature 0..255
        const int b = g >> 5, a = (g >> 3) & 3, z = g & 7;
        const int base = PREFIX(b), bc = COUNT(b);
        const int zh = z >> 1, hi16 = (z & 1);
        float acc = 0.f;
        #pragma unroll 4
        for (int q = base; q < base + bc; ++q) {
            unsigned uf = s_rec[q*8 + zh];
            float f1 = __uint_as_float(hi16 ? (uf & 0xFFFF0000u) : (uf << 16));
            float f2 = __uint_as_float(s_rec[q*8 + 4 + a]);
            acc += f1 * f2;
        }
        oa[64 + g] = acc;
    }
    if (tid >= 192) {
        const int g = tid + 64;                        // feature 256..319
        const int b = g >> 5, a = (g >> 3) & 3, z = g & 7;
        const int base = PREFIX(b), bc = COUNT(b);
        const int zh = z >> 1, hi16 = (z & 1);
        float acc = 0.f;
        #pragma unroll 4
        for (int q = base; q < base + bc; ++q) {
            unsigned uf = s_rec[q*8 + zh];
            float f1 = __uint_as_float(hi16 ? (uf & 0xFFFF0000u) : (uf << 16));
            float f2 = __uint_as_float(s_rec[q*8 + 4 + a]);
            acc += f1 * f2;
        }
        oa[64 + g] = acc;
    }
    #undef PREFIX
    #undef COUNT
}

extern "C" void kernel_launch(void* const* d_in, const int* in_sizes, int n_in,
                              void* d_out, int out_size, void* d_ws, size_t ws_size,
                              hipStream_t stream) {
    const int*   species = (const int*)d_in[0];
    const float* coords  = (const float*)d_in[1];
    float*       out     = (float*)d_out;
    aev_kernel<<<NMOL * NATOMS, 256, 0, stream>>>(species, coords, out);
}

// Round 17
// 16.953 us; speedup vs baseline: 1.0083x; 1.0083x over previous
//
#include <hip/hip_runtime.h>
#include <math.h>

#define NATOMS 32
#define NMOL   64
#define MAXP   466     // >= C(31,2)=465
#define RCRf 5.2f
#define RCAf 3.5f

// One block per (molecule n, center atom i). 512 threads, TWO barriers, ZERO
// LDS atomics. Key idea: bucket-sort is FREE given species-major compaction --
// bucket counts are analytic (c(s,t)=ns*nt / C(ns,2)) and a canonical
// bucket-major enumeration gives slot == p in closed form.
// A (wave 0): per-atom setup; 4 ballots compact neighbors BY SPECIES into
//    s_catom/s_cfa; store n_s (int4).
// B (tid<cnt): bucket b via 9 compares on analytic prefixes; within-bucket
//    (u,v) by rcp-div (rect) or triangular decode (diag); gather; build
//    factorized record {f1[0..7], f2f[0..3]} f32; write at slot p (sorted!).
// E: tid<320 angular feature (b,a,z) scans [prefix(b), prefix(b)+count(b));
//    tid 320..383 radial; species out at tid 0.
__global__ __launch_bounds__(512) void aev_kernel(const int* __restrict__ species,
                                                  const float* __restrict__ coords,
                                                  float* __restrict__ out) {
    const int bid = blockIdx.x;
    const int n = bid >> 5;
    const int i = bid & 31;
    const int tid = threadIdx.x;

    __shared__ float4 s_catom[NATOMS];           // species-major compacted: dx,dy,dz,d
    __shared__ float  s_cfa[NATOMS];             // compacted fca
    __shared__ float2 s_dfr[NATOMS];             // orig idx: d, fcr (radial)
    __shared__ int    s_sp[NATOMS];
    __shared__ int4   s_ns;                      // per-species neighbor counts
    __shared__ __align__(16) float s_rec[MAXP*12];   // f1[0..7], f2f[0..3]

    // ---------- phase A (wave 0) ----------
    if (tid < 64) {
        float fca_v = 0.f;
        int   spv = 0;
        float4 av = make_float4(0.f, 0.f, 0.f, 0.f);
        if (tid < NATOMS) {
            const float* cb = coords + (size_t)n*NATOMS*3;
            float dx = cb[tid*3+0] - cb[i*3+0];
            float dy = cb[tid*3+1] - cb[i*3+1];
            float dz = cb[tid*3+2] - cb[i*3+2];
            float d2 = dx*dx + dy*dy + dz*dz;
            float d  = sqrtf(d2 > 0.f ? d2 : 1.f);   // ref's where(d2>0,d2,1) guard
            bool self = (tid == i);
            float fr = (!self && d <= RCRf) ? (0.5f*__cosf(((float)M_PI/RCRf)*d) + 0.5f) : 0.f;
            fca_v    = (!self && d <= RCAf) ? (0.5f*__cosf(((float)M_PI/RCAf)*d) + 0.5f) : 0.f;
            spv = species[n*NATOMS + tid];
            s_dfr[tid] = make_float2(d, fr);
            s_sp[tid]  = spv;
            av = make_float4(dx, dy, dz, d);
        }
        // species-major compaction: 4 full-wave ballots
        const unsigned long long ltm = (1ull << tid) - 1ull;
        int base = 0, pos = -1;
        int cn[4];
        #pragma unroll
        for (int s = 0; s < 4; ++s) {
            unsigned long long ms = __ballot(fca_v > 0.f && spv == s);
            if (fca_v > 0.f && spv == s) pos = base + (int)__popcll(ms & ltm);
            cn[s] = (int)__popcll(ms);
            base += cn[s];
        }
        if (pos >= 0) { s_catom[pos] = av; s_cfa[pos] = fca_v; }
        if (tid == 0) s_ns = make_int4(cn[0], cn[1], cn[2], cn[3]);
    }
    __syncthreads();                                   // barrier 1

    // analytic bucket structure from 4 broadcast ints
    const int n0 = s_ns.x, n1 = s_ns.y, n2 = s_ns.z, n3 = s_ns.w;
    const int c0 = (n0*(n0-1))>>1, c1 = n0*n1, c2 = n0*n2, c3 = n0*n3;
    const int c4 = (n1*(n1-1))>>1, c5 = n1*n2, c6 = n1*n3;
    const int c7 = (n2*(n2-1))>>1, c8 = n2*n3, c9 = (n3*(n3-1))>>1;
    const int p1 = c0,      p2 = p1+c1, p3 = p2+c2, p4 = p3+c3, p5 = p4+c4;
    const int p6 = p5+c5,   p7 = p6+c6, p8 = p7+c7, p9 = p8+c8;
    const int cnt = p9 + c9;
    const int sb1 = n0, sb2 = n0+n1, sb3 = n0+n1+n2;   // species bases (sb0=0)

    const float CZ[8] = { 0.98078528f,  0.83146961f,  0.55557023f,  0.19509032f,
                         -0.19509032f, -0.55557023f, -0.83146961f, -0.98078528f};
    const float SZ[8] = { 0.19509032f,  0.55557023f,  0.83146961f,  0.98078528f,
                          0.98078528f,  0.83146961f,  0.55557023f,  0.19509032f};
    const float SHA[4] = {0.9f, 1.55f, 2.2f, 2.85f};

    // ---------- phase B: closed-form slot, no atomics ----------
    if (tid < cnt) {
        const int p = tid;
        // bucket via 9 branchless compares
        int b = (p>=p1)+(p>=p2)+(p>=p3)+(p>=p4)+(p>=p5)+(p>=p6)+(p>=p7)+(p>=p8)+(p>=p9);
        int bb = b==0?0 : b==1?p1 : b==2?p2 : b==3?p3 : b==4?p4
               : b==5?p5 : b==6?p6 : b==7?p7 : b==8?p8 : p9;
        int r = p - bb;
        int s = (b<4)?0 : (b<7)?1 : (b<9)?2 : 3;
        int fs = (s==0)?0 : (s==1)?4 : (s==2)?7 : 9;
        int t = b - fs + s;
        int ns_ = (s==0)?n0 : (s==1)?n1 : (s==2)?n2 : n3;
        int nt_ = (t==0)?n0 : (t==1)?n1 : (t==2)?n2 : n3;
        int sbs = (s==0)?0 : (s==1)?sb1 : (s==2)?sb2 : sb3;
        int sbt = (t==0)?0 : (t==1)?sb1 : (t==2)?sb2 : sb3;
        int u, v;
        if (s == t) {                                  // diagonal: u<v over ns_
            int Ms = 2*ns_ - 1;
            float tf = sqrtf((float)(Ms*Ms - 8*r));
            u = (int)(((float)Ms - tf) * 0.5f);
            u = max(0, min(u, ns_-2));
            while (u*(2*ns_-u-1)/2 > r) --u;           // <=2 fixup steps
            while ((u+1)*(2*ns_-u-2)/2 <= r) ++u;
            v = r - u*(2*ns_-u-1)/2 + u + 1;
        } else {                                       // rectangular: r = u*nt_+v
            u = (int)((float)r * __builtin_amdgcn_rcpf((float)nt_));
            if (u*nt_ > r) --u;
            if ((u+1)*nt_ <= r) ++u;
            v = r - u*nt_;
        }
        int jj = sbs + u, kk = sbt + v;
        float4 aj = s_catom[jj], ak = s_catom[kk];
        float fc2 = 2.f * s_cfa[jj] * s_cfa[kk];
        float dot = aj.x*ak.x + aj.y*ak.y + aj.z*ak.z;
        float cv = 0.95f * dot * __builtin_amdgcn_rcpf(aj.w * ak.w);
        cv = fminf(0.95f, fmaxf(-0.95f, cv));
        float sv = sqrtf(1.f - cv*cv);                 // sin(acos(c))
        float dmean = 0.5f * (aj.w + ak.w);
        float4 v0, v1, v2;
        v0.x = 0.5f + 0.5f*(cv*CZ[0] + sv*SZ[0]);
        v0.y = 0.5f + 0.5f*(cv*CZ[1] + sv*SZ[1]);
        v0.z = 0.5f + 0.5f*(cv*CZ[2] + sv*SZ[2]);
        v0.w = 0.5f + 0.5f*(cv*CZ[3] + sv*SZ[3]);
        v1.x = 0.5f + 0.5f*(cv*CZ[4] + sv*SZ[4]);
        v1.y = 0.5f + 0.5f*(cv*CZ[5] + sv*SZ[5]);
        v1.z = 0.5f + 0.5f*(cv*CZ[6] + sv*SZ[6]);
        v1.w = 0.5f + 0.5f*(cv*CZ[7] + sv*SZ[7]);
        #define POW32(q) { q = q*q; q = q*q; q = q*q; q = q*q; q = q*q; }
        POW32(v0.x) POW32(v0.y) POW32(v0.z) POW32(v0.w)
        POW32(v1.x) POW32(v1.y) POW32(v1.z) POW32(v1.w)
        #undef POW32
        float dm0 = dmean - SHA[0], dm1 = dmean - SHA[1];
        float dm2 = dmean - SHA[2], dm3 = dmean - SHA[3];
        v2.x = __expf(-8.f*dm0*dm0) * fc2;
        v2.y = __expf(-8.f*dm1*dm1) * fc2;
        v2.z = __expf(-8.f*dm2*dm2) * fc2;
        v2.w = __expf(-8.f*dm3*dm3) * fc2;
        float* rp = &s_rec[p*12];                      // slot == p (bucket-major)
        *(float4*)(rp+0) = v0;
        *(float4*)(rp+4) = v1;
        *(float4*)(rp+8) = v2;
    }
    __syncthreads();                                   // barrier 2

    // ---------- phase E ----------
    float* oa = out + NMOL*NATOMS + (size_t)bid * 384;

    if (tid < 320) {
        const int b = tid >> 5;
        const int a = (tid >> 3) & 3;
        const int z = tid & 7;
        const int base = b==0?0 : b==1?p1 : b==2?p2 : b==3?p3 : b==4?p4
                       : b==5?p5 : b==6?p6 : b==7?p7 : b==8?p8 : p9;
        const int bc   = b==0?c0 : b==1?c1 : b==2?c2 : b==3?c3 : b==4?c4
                       : b==5?c5 : b==6?c6 : b==7?c7 : b==8?c8 : c9;
        float acc = 0.f;
        #pragma unroll 4
        for (int q = base; q < base + bc; ++q)
            acc += s_rec[q*12 + z] * s_rec[q*12 + 8 + a];
        oa[64 + tid] = acc;
        if (tid == 0) out[bid] = (float)s_sp[i];       // output 0: species
    } else if (tid < 384) {
        const int f  = tid - 320;
        const int rs = f >> 4;
        const float shr = 0.9f + 0.26875f * (float)(f & 15);   // SHF_R
        float racc = 0.f;
        #pragma unroll 8
        for (int j = 0; j < NATOMS; ++j) {
            float2 dfr = s_dfr[j];                     // fr==0 encodes mask
            float dmr = dfr.x - shr;
            racc += (s_sp[j] == rs) ? 0.25f * __expf(-16.f*dmr*dmr) * dfr.y : 0.f;
        }
        oa[f] = racc;
    }
}

extern "C" void kernel_launch(void* const* d_in, const int* in_sizes, int n_in,
                              void* d_out, int out_size, void* d_ws, size_t ws_size,
                              hipStream_t stream) {
    const int*   species = (const int*)d_in[0];
    const float* coords  = (const float*)d_in[1];
    float*       out     = (float*)d_out;
    aev_kernel<<<NMOL * NATOMS, 512, 0, stream>>>(species, coords, out);
}

// Round 18
// 16.023 us; speedup vs baseline: 1.0668x; 1.0580x over previous
//
#include <hip/hip_runtime.h>
#include <math.h>

#define NATOMS 32
#define NMOL   64
#define MAXP   466     // >= C(31,2)=465
#define RCRf 5.2f
#define RCAf 3.5f

// R12 chassis + compact-indexed atom storage (no s_nbr indirection).
// One block per (molecule n, center atom i). 512 threads (8 waves), 3 barriers.
// A (wave 0): atom setup; ballot compaction writes atom data AT the compact
//    slot (s_catom/s_cfs) -- B gathers directly, one LDS hop.
// B (tid<cnt, single pass since cnt<=465<512): decode pair in compacted space,
//    build factorized record {f1[0..7], f2f[0..3]} in registers, histogram px.
// C: slot = register prefix of broadcast counts + atomicAdd rank; 3x b128.
// E: tid<320 owns angular feature (b=tid>>5, a, z), scans only bucket b
//    (2 LDS reads + fma per record). tid 320..383: radial features.
__global__ __launch_bounds__(512) void aev_kernel(const int* __restrict__ species,
                                                  const float* __restrict__ coords,
                                                  float* __restrict__ out) {
    const int bid = blockIdx.x;
    const int n = bid >> 5;
    const int i = bid & 31;
    const int tid = threadIdx.x;

    __shared__ float4 s_catom[NATOMS];           // compacted: dx, dy, dz, d
    __shared__ float2 s_cfs[NATOMS];             // compacted: fca, species(float)
    __shared__ float2 s_dfr[NATOMS];             // orig idx: d, fcr (radial)
    __shared__ int    s_sp[NATOMS];
    __shared__ int    s_nn;
    __shared__ __align__(16) float s_rec[MAXP*12];   // f1[0..7], f2f[0..3]
    __shared__ int    s_cnt[10], s_rank[10];

    // ---------- phase A (wave 0) ----------
    if (tid < 10) { s_cnt[tid] = 0; s_rank[tid] = 0; }
    if (tid < 64) {
        float fca_v = 0.f, sv = 0.f;
        float4 av = make_float4(0.f, 0.f, 0.f, 0.f);
        if (tid < NATOMS) {
            const float* cb = coords + (size_t)n*NATOMS*3;
            float dx = cb[tid*3+0] - cb[i*3+0];
            float dy = cb[tid*3+1] - cb[i*3+1];
            float dz = cb[tid*3+2] - cb[i*3+2];
            float d2 = dx*dx + dy*dy + dz*dz;
            float d  = sqrtf(d2 > 0.f ? d2 : 1.f);   // ref's where(d2>0,d2,1) guard
            bool self = (tid == i);
            float fr = (!self && d <= RCRf) ? (0.5f*__cosf(((float)M_PI/RCRf)*d) + 0.5f) : 0.f;
            fca_v    = (!self && d <= RCAf) ? (0.5f*__cosf(((float)M_PI/RCAf)*d) + 0.5f) : 0.f;
            int spv = species[n*NATOMS + tid];
            s_dfr[tid] = make_float2(d, fr);
            s_sp[tid]  = spv;
            av = make_float4(dx, dy, dz, d);
            sv = (float)spv;
        }
        unsigned long long m = __ballot(fca_v > 0.f);  // full-wave-active context
        int ci = (int)__popcll(m & ((1ull << tid) - 1ull));
        if (fca_v > 0.f) { s_catom[ci] = av; s_cfs[ci] = make_float2(fca_v, sv); }
        if (tid == 0) s_nn = (int)__popcll(m);
    }
    __syncthreads();                                   // barrier 1

    const int nn  = s_nn;
    const int cnt = (nn*(nn-1)) >> 1;                  // <= 465 < 512: single pass
    const int M   = 2*nn - 1;

    const float CZ[8] = { 0.98078528f,  0.83146961f,  0.55557023f,  0.19509032f,
                         -0.19509032f, -0.55557023f, -0.83146961f, -0.98078528f};
    const float SZ[8] = { 0.19509032f,  0.55557023f,  0.83146961f,  0.98078528f,
                          0.98078528f,  0.83146961f,  0.55557023f,  0.19509032f};
    const float SHA[4] = {0.9f, 1.55f, 2.2f, 2.85f};

    // ---------- phase B: record build in registers + histogram ----------
    int px = -1;
    float4 v0, v1, v2;
    if (tid < cnt) {
        float t = sqrtf((float)(M*M - 8*tid));
        int jj = (int)(((float)M - t) * 0.5f);
        jj = max(0, min(jj, nn-2));
        while (jj*(2*nn-jj-1)/2 > tid) --jj;           // <=2 fixup steps
        while ((jj+1)*(2*nn-jj-2)/2 <= tid) ++jj;
        int kk = tid - jj*(2*nn-jj-1)/2 + jj + 1;
        float4 aj = s_catom[jj], ak = s_catom[kk];     // direct compact gather
        float2 fj = s_cfs[jj],  fk = s_cfs[kk];
        float fc2 = 2.f * fj.x * fk.x;
        float dot = aj.x*ak.x + aj.y*ak.y + aj.z*ak.z;
        float c = 0.95f * dot * __builtin_amdgcn_rcpf(aj.w * ak.w);
        c = fminf(0.95f, fmaxf(-0.95f, c));
        float s = sqrtf(1.f - c*c);                    // sin(acos(c))
        float dmean = 0.5f * (aj.w + ak.w);
        int sj = (int)fj.y, sk = (int)fk.y;
        int lo = min(sj, sk), hi = max(sj, sk);
        px = ((lo*(9-lo)) >> 1) + (hi - lo);           // triu pair index, S=4
        v0.x = 0.5f + 0.5f*(c*CZ[0] + s*SZ[0]);
        v0.y = 0.5f + 0.5f*(c*CZ[1] + s*SZ[1]);
        v0.z = 0.5f + 0.5f*(c*CZ[2] + s*SZ[2]);
        v0.w = 0.5f + 0.5f*(c*CZ[3] + s*SZ[3]);
        v1.x = 0.5f + 0.5f*(c*CZ[4] + s*SZ[4]);
        v1.y = 0.5f + 0.5f*(c*CZ[5] + s*SZ[5]);
        v1.z = 0.5f + 0.5f*(c*CZ[6] + s*SZ[6]);
        v1.w = 0.5f + 0.5f*(c*CZ[7] + s*SZ[7]);
        #define POW32(q) { q = q*q; q = q*q; q = q*q; q = q*q; q = q*q; }
        POW32(v0.x) POW32(v0.y) POW32(v0.z) POW32(v0.w)
        POW32(v1.x) POW32(v1.y) POW32(v1.z) POW32(v1.w)
        #undef POW32
        float dm0 = dmean - SHA[0], dm1 = dmean - SHA[1];
        float dm2 = dmean - SHA[2], dm3 = dmean - SHA[3];
        v2.x = __expf(-8.f*dm0*dm0) * fc2;
        v2.y = __expf(-8.f*dm1*dm1) * fc2;
        v2.z = __expf(-8.f*dm2*dm2) * fc2;
        v2.w = __expf(-8.f*dm3*dm3) * fc2;
        atomicAdd(&s_cnt[px], 1);
    }
    __syncthreads();                                   // barrier 2

    // counts complete: every thread reads them (broadcast) for prefix math
    int c0 = s_cnt[0], c1 = s_cnt[1], c2 = s_cnt[2], c3 = s_cnt[3], c4 = s_cnt[4];
    int c5 = s_cnt[5], c6 = s_cnt[6], c7 = s_cnt[7], c8 = s_cnt[8], c9 = s_cnt[9];

    // ---------- phase C: slot = prefix + rank; write record ----------
    if (px >= 0) {
        int base = 0;
        base += (px > 0) ? c0 : 0;  base += (px > 1) ? c1 : 0;
        base += (px > 2) ? c2 : 0;  base += (px > 3) ? c3 : 0;
        base += (px > 4) ? c4 : 0;  base += (px > 5) ? c5 : 0;
        base += (px > 6) ? c6 : 0;  base += (px > 7) ? c7 : 0;
        base += (px > 8) ? c8 : 0;
        int slot = base + atomicAdd(&s_rank[px], 1);
        float* r = &s_rec[slot*12];
        *(float4*)(r+0) = v0;
        *(float4*)(r+4) = v1;
        *(float4*)(r+8) = v2;
    }
    __syncthreads();                                   // barrier 3

    // ---------- phase E ----------
    float* oa = out + NMOL*NATOMS + (size_t)bid * 384;

    if (tid < 320) {
        const int b = tid >> 5;
        const int a = (tid >> 3) & 3;
        const int z = tid & 7;
        int base = 0;
        base += (b > 0) ? c0 : 0;  base += (b > 1) ? c1 : 0;
        base += (b > 2) ? c2 : 0;  base += (b > 3) ? c3 : 0;
        base += (b > 4) ? c4 : 0;  base += (b > 5) ? c5 : 0;
        base += (b > 6) ? c6 : 0;  base += (b > 7) ? c7 : 0;
        base += (b > 8) ? c8 : 0;
        int bc = b==0?c0 : b==1?c1 : b==2?c2 : b==3?c3 : b==4?c4
               : b==5?c5 : b==6?c6 : b==7?c7 : b==8?c8 : c9;
        float acc = 0.f;
        #pragma unroll 4
        for (int q = base; q < base + bc; ++q)
            acc += s_rec[q*12 + z] * s_rec[q*12 + 8 + a];
        oa[64 + tid] = acc;
        if (tid == 0) out[bid] = (float)s_sp[i];       // output 0: species
    } else if (tid < 384) {
        const int f  = tid - 320;
        const int rs = f >> 4;
        const float shr = 0.9f + 0.26875f * (float)(f & 15);   // SHF_R
        float racc = 0.f;
        #pragma unroll 8
        for (int j = 0; j < NATOMS; ++j) {
            float2 dfr = s_dfr[j];                     // fr==0 encodes mask
            float dmr = dfr.x - shr;
            racc += (s_sp[j] == rs) ? 0.25f * __expf(-16.f*dmr*dmr) * dfr.y : 0.f;
        }
        oa[f] = racc;
    }
}

extern "C" void kernel_launch(void* const* d_in, const int* in_sizes, int n_in,
                              void* d_out, int out_size, void* d_ws, size_t ws_size,
                              hipStream_t stream) {
    const int*   species = (const int*)d_in[0];
    const float* coords  = (const float*)d_in[1];
    float*       out     = (float*)d_out;
    aev_kernel<<<NMOL * NATOMS, 512, 0, stream>>>(species, coords, out);
}